// Round 1
// baseline (994.037 us; speedup 1.0000x reference)
//
#include <hip/hip_runtime.h>
#include <cmath>

#define PI_D 3.14159265358979323846

static constexpr int B_ = 4, H_ = 128, W_ = 128, C_ = 768, WF = 65;
static constexpr size_t PLANE = (size_t)B_ * H_ * WF * C_;  // 25,559,040 elems
static constexpr float LAMBDA_ = 0.01f;

using short8  = __attribute__((ext_vector_type(8))) short;
using floatx4 = __attribute__((ext_vector_type(4))) float;

__device__ __forceinline__ float2 cmul(float2 a, float2 b) {
  return make_float2(a.x * b.x - a.y * b.y, a.x * b.y + a.y * b.x);
}

// ---------------- 64-pt complex FFT, fully unrolled, in registers ----------
// SIGN=-1: forward (raw DFT sum), SIGN=+1: inverse (raw sum, no 1/N)
template<int SIGN, int S>
__device__ __forceinline__ void fft64_stage(float2* z, const float2* tw) {
  constexpr int half = 1 << S;
  #pragma unroll
  for (int g = 0; g < 32; ++g) {
    const int j  = g & (half - 1);
    const int i0 = ((g >> S) << (S + 1)) + j;
    const int i1 = i0 + half;
    float2 w = tw[j << (5 - S)];      // exp(-2*pi*i*j/(2*half))
    if (SIGN > 0) w.y = -w.y;
    float2 t = cmul(w, z[i1]);
    float2 a = z[i0];
    z[i0] = make_float2(a.x + t.x, a.y + t.y);
    z[i1] = make_float2(a.x - t.x, a.y - t.y);
  }
}

template<int SIGN>
__device__ __forceinline__ void fft64(float2* z, const float2* tw) {
  #pragma unroll
  for (int i = 0; i < 64; ++i) {
    const int j = ((i >> 5) & 1) | (((i >> 4) & 1) << 1) | (((i >> 3) & 1) << 2)
                | (((i >> 2) & 1) << 3) | (((i >> 1) & 1) << 4) | ((i & 1) << 5);
    if (i < j) { float2 t = z[i]; z[i] = z[j]; z[j] = t; }
  }
  fft64_stage<SIGN, 0>(z, tw);
  fft64_stage<SIGN, 1>(z, tw);
  fft64_stage<SIGN, 2>(z, tw);
  fft64_stage<SIGN, 3>(z, tw);
  fft64_stage<SIGN, 4>(z, tw);
  fft64_stage<SIGN, 5>(z, tw);
}

// ---------------- twiddle init (runs every launch; graph-capture safe) ----
__global__ void k_init_tw(float2* tw64, float2* tw128) {
  int t = threadIdx.x;
  if (t < 32) {
    double th = -2.0 * PI_D * (double)t / 64.0;
    tw64[t] = make_float2((float)cos(th), (float)sin(th));
  }
  if (t < 65) {
    double th = -PI_D * (double)t / 64.0;   // W_128^t
    tw128[t] = make_float2((float)cos(th), (float)sin(th));
  }
}

// ---------------- kernel 1: rfft along W (raw sums) ------------------------
// one thread per (b,h,c) row of 128 reals -> 65 complex
__global__ __launch_bounds__(256) void k_rfft_w(
    const float* __restrict__ x, float* __restrict__ Xr, float* __restrict__ Xi,
    const float2* __restrict__ tw64g, const float2* __restrict__ tw128g) {
  __shared__ float2 stw64[32];
  __shared__ float2 stw128[65];
  const int tid = threadIdx.x;
  if (tid < 32) stw64[tid]  = tw64g[tid];
  if (tid < 65) stw128[tid] = tw128g[tid];
  __syncthreads();
  const int blk = blockIdx.x;            // (b*H + h)*3 + cc
  const int cc = blk % 3, bh = blk / 3;
  const int c = cc * 256 + tid;
  const float* xp = x + (size_t)bh * (W_ * C_) + c;
  float2 z[64];
  #pragma unroll
  for (int n = 0; n < 64; ++n) {         // z[n] = x[2n] + i x[2n+1]
    z[n].x = xp[(size_t)(2 * n) * C_];
    z[n].y = xp[(size_t)(2 * n + 1) * C_];
  }
  fft64<-1>(z, stw64);
  const size_t obase = (size_t)bh * (WF * C_) + c;
  #pragma unroll
  for (int k = 0; k <= 64; ++k) {        // real-FFT untangle
    float2 a  = z[k & 63];
    float2 bq = z[(64 - k) & 63];
    float2 ze = make_float2(0.5f * (a.x + bq.x), 0.5f * (a.y - bq.y));
    float2 d  = make_float2(0.5f * (a.x - bq.x), 0.5f * (a.y + bq.y));
    float2 zo = make_float2(d.y, -d.x);  // -i*d
    float2 w  = stw128[k];
    float2 X  = make_float2(ze.x + w.x * zo.x - w.y * zo.y,
                            ze.y + w.x * zo.y + w.y * zo.x);
    Xr[obase + (size_t)k * C_] = X.x;
    Xi[obase + (size_t)k * C_] = X.y;
  }
}

// ---------------- kernel 2/4: 128-pt FFT along H, in place -----------------
// SIGN=-1 forward (applies 1/128 ortho-fwd scale), SIGN=+1 inverse (no scale)
// 128 threads: wave0 = even samples/bins, wave1 = odd; 64 channels per block
template<int SIGN>
__global__ __launch_bounds__(128) void k_fft_h(
    float* __restrict__ Xr, float* __restrict__ Xi,
    const float2* __restrict__ tw64g, const float2* __restrict__ tw128g) {
  __shared__ float2 stw64[32];
  __shared__ float2 stw128[65];
  __shared__ float2 Elds[64][64];
  const int tid = threadIdx.x;
  if (tid < 32) stw64[tid]  = tw64g[tid];
  if (tid < 65) stw128[tid] = tw128g[tid];
  __syncthreads();
  const int half = tid >> 6, lane = tid & 63;
  const int blk = blockIdx.x;            // b*(65*12) + wf*12 + cc
  const int cc = blk % 12;
  const int t2 = blk / 12;
  const int wf = t2 % 65, b = t2 / 65;
  const int c = cc * 64 + lane;
  const size_t base = ((size_t)b * (H_ * WF) + wf) * C_ + c;   // h = 0 element
  const size_t hstr = (size_t)WF * C_;
  float2 z[64];
  #pragma unroll
  for (int n = 0; n < 64; ++n) {
    const size_t a = base + (size_t)(2 * n + half) * hstr;
    z[n].x = Xr[a]; z[n].y = Xi[a];
  }
  fft64<SIGN>(z, stw64);
  if (half == 0) {
    #pragma unroll
    for (int k = 0; k < 64; ++k) Elds[k][lane] = z[k];
  } else {
    #pragma unroll
    for (int k = 0; k < 64; ++k) {       // T[k] = W128^{±k} * O[k]
      float2 w = stw128[k];
      if (SIGN > 0) w.y = -w.y;
      z[k] = cmul(w, z[k]);
    }
  }
  __syncthreads();
  if (half == 1) {
    const float scale = (SIGN < 0) ? (1.0f / 128.0f) : 1.0f;
    #pragma unroll
    for (int k = 0; k < 64; ++k) {
      float2 E = Elds[k][lane];
      float2 t = z[k];
      const size_t a0 = base + (size_t)k * hstr;
      const size_t a1 = base + (size_t)(k + 64) * hstr;
      Xr[a0] = (E.x + t.x) * scale; Xi[a0] = (E.y + t.y) * scale;
      Xr[a1] = (E.x - t.x) * scale; Xi[a1] = (E.y - t.y) * scale;
    }
  }
}

// ---------------- kernel 3: block-diagonal complex MLP (bf16 MFMA) ---------
__device__ __forceinline__ short f2bf(float f) {
  union { float f; unsigned u; } v; v.f = f;
  unsigned r = v.u + 0x7FFFu + ((v.u >> 16) & 1u);   // RNE
  return (short)(r >> 16);
}
__device__ __forceinline__ float softshrink(float v) {
  return v > LAMBDA_ ? v - LAMBDA_ : (v < -LAMBDA_ ? v + LAMBDA_ : 0.0f);
}

static constexpr int LDW = 104;   // weight K-stride (bf16), pad vs 96 for banks
static constexpr int OST = 200;   // obuf row stride (bf16)

// LDS layout (shorts): wr[96*104] | wi[96*104] | obuf[64*200]  == 65,536 B
__global__ __launch_bounds__(256) void k_mlp(
    float* __restrict__ Xr, float* __restrict__ Xi,
    const float* __restrict__ w1, const float* __restrict__ w2,
    const float* __restrict__ b1, const float* __restrict__ b2) {
  __shared__ __align__(16) short smem[32768];
  short* wr   = smem;
  short* wi   = smem + 9984;
  short* obuf = smem + 19968;
  const int tid  = threadIdx.x;
  const int kb   = blockIdx.x & 7;
  const int p0   = (blockIdx.x >> 3) * 64;
  const int wv   = tid >> 6, lane = tid & 63;
  const int quad = lane >> 4, l16 = lane & 15;

  floatx4 acc[12];

  // layer-1 weights -> LDS, transposed [o][i], bf16
  {
    const float* wrg = w1 + (size_t)kb * 9216;
    const float* wig = w1 + (size_t)(8 + kb) * 9216;
    for (int idx = tid; idx < 9216; idx += 256) {
      int i = idx / 96, o = idx - i * 96;
      wr[o * LDW + i] = f2bf(wrg[idx]);
      wi[o * LDW + i] = f2bf(wig[idx]);
    }
  }
  __syncthreads();

  // ---- GEMM1: [64 x 192] = X * Wc1 ----
  #pragma unroll
  for (int nt = 0; nt < 12; ++nt) acc[nt] = (floatx4){0.f, 0.f, 0.f, 0.f};
  #pragma unroll
  for (int c = 0; c < 6; ++c) {
    const int  koff = (c % 3) * 32 + quad * 8;
    const bool kh   = c >= 3;
    const float* plane = kh ? Xi : Xr;
    const int p = p0 + wv * 16 + l16;
    const float* src = plane + (size_t)p * C_ + kb * 96 + koff;
    float4 u0 = *(const float4*)src;
    float4 u1 = *(const float4*)(src + 4);
    short8 afr;
    afr[0] = f2bf(u0.x); afr[1] = f2bf(u0.y); afr[2] = f2bf(u0.z); afr[3] = f2bf(u0.w);
    afr[4] = f2bf(u1.x); afr[5] = f2bf(u1.y); afr[6] = f2bf(u1.z); afr[7] = f2bf(u1.w);
    #pragma unroll
    for (int nt = 0; nt < 12; ++nt) {
      const bool nh = nt >= 6;
      const short* buf = (nh != kh) ? wi : wr;
      const int row = (nt % 6) * 16 + l16;
      short8 bfr = *(const short8*)&buf[row * LDW + koff];
      if (kh && !nh) {                    // -Wi quadrant: flip bf16 signs
        union { short8 s; int v[4]; } u; u.s = bfr;
        u.v[0] ^= 0x80008000; u.v[1] ^= 0x80008000;
        u.v[2] ^= 0x80008000; u.v[3] ^= 0x80008000;
        bfr = u.s;
      }
      acc[nt] = __builtin_amdgcn_mfma_f32_16x16x32_bf16(afr, bfr, acc[nt], 0, 0, 0);
    }
  }
  // epilogue 1: bias + softshrink -> obuf (bf16, A-layout for GEMM2)
  #pragma unroll
  for (int nt = 0; nt < 12; ++nt) {
    const int n = nt * 16 + l16;
    const int part = (nt >= 6) ? 1 : 0;
    const float bs = b1[(part * 8 + kb) * 96 + (n - part * 96)];
    #pragma unroll
    for (int r = 0; r < 4; ++r) {
      const int m = wv * 16 + quad * 4 + r;
      obuf[m * OST + n] = f2bf(softshrink(acc[nt][r] + bs));
    }
  }
  __syncthreads();
  // layer-2 weights overwrite layer-1 in LDS
  {
    const float* wrg = w2 + (size_t)kb * 9216;
    const float* wig = w2 + (size_t)(8 + kb) * 9216;
    for (int idx = tid; idx < 9216; idx += 256) {
      int i = idx / 96, o = idx - i * 96;
      wr[o * LDW + i] = f2bf(wrg[idx]);
      wi[o * LDW + i] = f2bf(wig[idx]);
    }
  }
  __syncthreads();
  // ---- GEMM2: A from obuf ----
  #pragma unroll
  for (int nt = 0; nt < 12; ++nt) acc[nt] = (floatx4){0.f, 0.f, 0.f, 0.f};
  #pragma unroll
  for (int c = 0; c < 6; ++c) {
    const int  koff = (c % 3) * 32 + quad * 8;
    const bool kh   = c >= 3;
    const int m = wv * 16 + l16;
    short8 afr = *(const short8*)&obuf[m * OST + c * 32 + quad * 8];
    #pragma unroll
    for (int nt = 0; nt < 12; ++nt) {
      const bool nh = nt >= 6;
      const short* buf = (nh != kh) ? wi : wr;
      const int row = (nt % 6) * 16 + l16;
      short8 bfr = *(const short8*)&buf[row * LDW + koff];
      if (kh && !nh) {
        union { short8 s; int v[4]; } u; u.s = bfr;
        u.v[0] ^= 0x80008000; u.v[1] ^= 0x80008000;
        u.v[2] ^= 0x80008000; u.v[3] ^= 0x80008000;
        bfr = u.s;
      }
      acc[nt] = __builtin_amdgcn_mfma_f32_16x16x32_bf16(afr, bfr, acc[nt], 0, 0, 0);
    }
  }
  // epilogue 2: bias + softshrink -> spectrum (in place)
  #pragma unroll
  for (int nt = 0; nt < 12; ++nt) {
    const int n = nt * 16 + l16;
    const int part = (nt >= 6) ? 1 : 0;
    const int o = n - part * 96;
    const float bs = b2[(part * 8 + kb) * 96 + o];
    float* plane = part ? Xi : Xr;
    #pragma unroll
    for (int r = 0; r < 4; ++r) {
      const int m = wv * 16 + quad * 4 + r;
      const int p = p0 + m;
      plane[(size_t)p * C_ + kb * 96 + o] = softshrink(acc[nt][r] + bs);
    }
  }
}

// ---------------- kernel 5: irfft along W + residual -----------------------
__global__ __launch_bounds__(256) void k_irfft_w(
    const float* __restrict__ Xr, const float* __restrict__ Xi,
    const float* __restrict__ xin, float* __restrict__ y,
    const float2* __restrict__ tw64g, const float2* __restrict__ tw128g) {
  __shared__ float2 stw64[32];
  __shared__ float2 stw128[65];
  const int tid = threadIdx.x;
  if (tid < 32) stw64[tid]  = tw64g[tid];
  if (tid < 65) stw128[tid] = tw128g[tid];
  __syncthreads();
  const int blk = blockIdx.x;
  const int cc = blk % 3, bh = blk / 3;
  const int c = cc * 256 + tid;
  const size_t ibase = (size_t)bh * (WF * C_) + c;
  float2 z[64];
  {
    // bins 0 and 64: imag parts dropped (numpy c2r semantics)
    float x0r  = Xr[ibase];
    float x64r = Xr[ibase + (size_t)64 * C_];
    z[0] = make_float2(0.5f * (x0r + x64r), 0.5f * (x0r - x64r));
  }
  #pragma unroll
  for (int k = 1; k <= 32; ++k) {
    float2 a, b;
    a.x = Xr[ibase + (size_t)k * C_];        a.y = Xi[ibase + (size_t)k * C_];
    b.x = Xr[ibase + (size_t)(64 - k) * C_]; b.y = Xi[ibase + (size_t)(64 - k) * C_];
    float2 s = make_float2(0.5f * (a.x + b.x), 0.5f * (a.y - b.y));
    float2 d = make_float2(0.5f * (a.x - b.x), 0.5f * (a.y + b.y));
    float2 w = stw128[k]; w.y = -w.y;        // conj(W128^k)
    float2 zo = cmul(w, d);
    z[k] = make_float2(s.x - zo.y, s.y + zo.x);         // s + i*zo
    if (k < 32) z[64 - k] = make_float2(s.x + zo.y, zo.x - s.y);  // conj(s)+i*conj(zo)
  }
  fft64<1>(z, stw64);
  const float* xb = xin + (size_t)bh * (W_ * C_) + c;
  float*       yb = y   + (size_t)bh * (W_ * C_) + c;
  #pragma unroll
  for (int n = 0; n < 64; ++n) {
    yb[(size_t)(2 * n) * C_]     = z[n].x * (1.0f / 64.0f) + xb[(size_t)(2 * n) * C_];
    yb[(size_t)(2 * n + 1) * C_] = z[n].y * (1.0f / 64.0f) + xb[(size_t)(2 * n + 1) * C_];
  }
}

extern "C" void kernel_launch(void* const* d_in, const int* in_sizes, int n_in,
                              void* d_out, int out_size, void* d_ws, size_t ws_size,
                              hipStream_t stream) {
  const float* x  = (const float*)d_in[0];
  const float* w1 = (const float*)d_in[1];
  const float* w2 = (const float*)d_in[2];
  const float* b1 = (const float*)d_in[3];
  const float* b2 = (const float*)d_in[4];
  float* y = (float*)d_out;

  float2* tw64  = (float2*)d_ws;
  float2* tw128 = tw64 + 32;
  float*  Xr = (float*)((char*)d_ws + 1024);
  float*  Xi = Xr + PLANE;

  k_init_tw<<<1, 128, 0, stream>>>(tw64, tw128);
  k_rfft_w<<<dim3(B_ * H_ * 3), dim3(256), 0, stream>>>(x, Xr, Xi, tw64, tw128);
  k_fft_h<-1><<<dim3(B_ * WF * 12), dim3(128), 0, stream>>>(Xr, Xi, tw64, tw128);
  k_mlp<<<dim3(520 * 8), dim3(256), 0, stream>>>(Xr, Xi, w1, w2, b1, b2);
  k_fft_h<1><<<dim3(B_ * WF * 12), dim3(128), 0, stream>>>(Xr, Xi, tw64, tw128);
  k_irfft_w<<<dim3(B_ * H_ * 3), dim3(256), 0, stream>>>(Xr, Xi, x, y, tw64, tw128);
}

// Round 2
// 824.147 us; speedup vs baseline: 1.2061x; 1.2061x over previous
//
#include <hip/hip_runtime.h>
#include <cmath>

#define PI_D 3.14159265358979323846

static constexpr int B_ = 4, H_ = 128, W_ = 128, C_ = 768, WF = 65;
static constexpr size_t PLANE = (size_t)B_ * H_ * WF * C_;  // 25,559,040 elems
static constexpr float LAMBDA_ = 0.01f;

using short8   = __attribute__((ext_vector_type(8))) short;
using floatx16 = __attribute__((ext_vector_type(16))) float;

__device__ __forceinline__ float2 cmul(float2 a, float2 b) {
  return make_float2(a.x * b.x - a.y * b.y, a.x * b.y + a.y * b.x);
}
__device__ __forceinline__ unsigned short f2bfu(float f) {
  union { float f; unsigned u; } v; v.f = f;
  unsigned r = v.u + 0x7FFFu + ((v.u >> 16) & 1u);   // RNE
  return (unsigned short)(r >> 16);
}
__device__ __forceinline__ float bf2f(unsigned short u) {
  union { unsigned u; float f; } v; v.u = (unsigned)u << 16;
  return v.f;
}
__device__ __forceinline__ float softshrink(float v) {
  return v > LAMBDA_ ? v - LAMBDA_ : (v < -LAMBDA_ ? v + LAMBDA_ : 0.0f);
}

// ---------------- 64-pt complex FFT, fully unrolled, in registers ----------
template<int SIGN, int S>
__device__ __forceinline__ void fft64_stage(float2* z, const float2* tw) {
  constexpr int half = 1 << S;
  #pragma unroll
  for (int g = 0; g < 32; ++g) {
    const int j  = g & (half - 1);
    const int i0 = ((g >> S) << (S + 1)) + j;
    const int i1 = i0 + half;
    float2 w = tw[j << (5 - S)];
    if (SIGN > 0) w.y = -w.y;
    float2 t = cmul(w, z[i1]);
    float2 a = z[i0];
    z[i0] = make_float2(a.x + t.x, a.y + t.y);
    z[i1] = make_float2(a.x - t.x, a.y - t.y);
  }
}
template<int SIGN>
__device__ __forceinline__ void fft64(float2* z, const float2* tw) {
  #pragma unroll
  for (int i = 0; i < 64; ++i) {
    const int j = ((i >> 5) & 1) | (((i >> 4) & 1) << 1) | (((i >> 3) & 1) << 2)
                | (((i >> 2) & 1) << 3) | (((i >> 1) & 1) << 4) | ((i & 1) << 5);
    if (i < j) { float2 t = z[i]; z[i] = z[j]; z[j] = t; }
  }
  fft64_stage<SIGN, 0>(z, tw);
  fft64_stage<SIGN, 1>(z, tw);
  fft64_stage<SIGN, 2>(z, tw);
  fft64_stage<SIGN, 3>(z, tw);
  fft64_stage<SIGN, 4>(z, tw);
  fft64_stage<SIGN, 5>(z, tw);
}

// ---------------- init: twiddles ------------------------------------------
__global__ void k_init_tw(float2* tw64, float2* tw128) {
  int t = threadIdx.x;
  if (t < 32) {
    double th = -2.0 * PI_D * (double)t / 64.0;
    tw64[t] = make_float2((float)cos(th), (float)sin(th));
  }
  if (t < 65) {
    double th = -PI_D * (double)t / 64.0;
    tw128[t] = make_float2((float)cos(th), (float)sin(th));
  }
}

// ---------------- init: weights fp32 -> bf16, transposed [o][104] ----------
// dst flat: (((layer*8 + kb)*2 + ri)*96 + o)*104 + i ; src w[ri][kb][i][o]
__global__ __launch_bounds__(256) void k_wconv(
    const float* __restrict__ w1, const float* __restrict__ w2,
    unsigned short* __restrict__ wbf) {
  const int flat = blockIdx.x * 256 + threadIdx.x;   // < 319488
  const int i  = flat % 104;
  const int t2 = flat / 104;
  const int o  = t2 % 96;
  const int t3 = t2 / 96;
  const int ri = t3 & 1;
  const int t4 = t3 >> 1;
  const int kb = t4 & 7;
  const int layer = t4 >> 3;
  const float* w = layer ? w2 : w1;
  unsigned short v = 0;
  if (i < 96) v = f2bfu(w[((size_t)(ri * 8 + kb) * 96 + i) * 96 + o]);
  wbf[flat] = v;
}

// ---------------- kernel 1: rfft along W, bf16 out -------------------------
__global__ __launch_bounds__(256) void k_rfft_w(
    const float* __restrict__ x,
    unsigned short* __restrict__ Sr, unsigned short* __restrict__ Si,
    const float2* __restrict__ tw64g, const float2* __restrict__ tw128g) {
  __shared__ float2 stw64[32];
  __shared__ float2 stw128[65];
  const int tid = threadIdx.x;
  if (tid < 32) stw64[tid]  = tw64g[tid];
  if (tid < 65) stw128[tid] = tw128g[tid];
  __syncthreads();
  const int blk = blockIdx.x;
  const int cc = blk % 3, bh = blk / 3;
  const int c = cc * 256 + tid;
  const float* xp = x + (size_t)bh * (W_ * C_) + c;
  float2 z[64];
  #pragma unroll
  for (int n = 0; n < 64; ++n) {
    z[n].x = xp[(size_t)(2 * n) * C_];
    z[n].y = xp[(size_t)(2 * n + 1) * C_];
  }
  fft64<-1>(z, stw64);
  const size_t obase = (size_t)bh * (WF * C_) + c;
  #pragma unroll
  for (int k = 0; k <= 64; ++k) {
    float2 a  = z[k & 63];
    float2 bq = z[(64 - k) & 63];
    float2 ze = make_float2(0.5f * (a.x + bq.x), 0.5f * (a.y - bq.y));
    float2 d  = make_float2(0.5f * (a.x - bq.x), 0.5f * (a.y + bq.y));
    float2 zo = make_float2(d.y, -d.x);
    float2 w  = stw128[k];
    float2 X  = make_float2(ze.x + w.x * zo.x - w.y * zo.y,
                            ze.y + w.x * zo.y + w.y * zo.x);
    Sr[obase + (size_t)k * C_] = f2bfu(X.x);
    Si[obase + (size_t)k * C_] = f2bfu(X.y);
  }
}

// ---------------- kernel 2/4: 128-pt FFT along H, bf16 in-place ------------
template<int SIGN>
__global__ __launch_bounds__(128) void k_fft_h(
    unsigned short* __restrict__ Sr, unsigned short* __restrict__ Si,
    const float2* __restrict__ tw64g, const float2* __restrict__ tw128g) {
  __shared__ float2 stw64[32];
  __shared__ float2 stw128[65];
  __shared__ float2 Elds[64][64];
  const int tid = threadIdx.x;
  if (tid < 32) stw64[tid]  = tw64g[tid];
  if (tid < 65) stw128[tid] = tw128g[tid];
  __syncthreads();
  const int half = tid >> 6, lane = tid & 63;
  const int blk = blockIdx.x;
  const int cc = blk % 12;
  const int t2 = blk / 12;
  const int wf = t2 % 65, b = t2 / 65;
  const int c = cc * 64 + lane;
  const size_t base = ((size_t)b * (H_ * WF) + wf) * C_ + c;
  const size_t hstr = (size_t)WF * C_;
  float2 z[64];
  #pragma unroll
  for (int n = 0; n < 64; ++n) {
    const size_t a = base + (size_t)(2 * n + half) * hstr;
    z[n].x = bf2f(Sr[a]); z[n].y = bf2f(Si[a]);
  }
  fft64<SIGN>(z, stw64);
  if (half == 0) {
    #pragma unroll
    for (int k = 0; k < 64; ++k) Elds[k][lane] = z[k];
  } else {
    #pragma unroll
    for (int k = 0; k < 64; ++k) {
      float2 w = stw128[k];
      if (SIGN > 0) w.y = -w.y;
      z[k] = cmul(w, z[k]);
    }
  }
  __syncthreads();
  if (half == 1) {
    const float scale = (SIGN < 0) ? (1.0f / 128.0f) : 1.0f;
    #pragma unroll
    for (int k = 0; k < 64; ++k) {
      float2 E = Elds[k][lane];
      float2 t = z[k];
      const size_t a0 = base + (size_t)k * hstr;
      const size_t a1 = base + (size_t)(k + 64) * hstr;
      Sr[a0] = f2bfu((E.x + t.x) * scale); Si[a0] = f2bfu((E.y + t.y) * scale);
      Sr[a1] = f2bfu((E.x - t.x) * scale); Si[a1] = f2bfu((E.y - t.y) * scale);
    }
  }
}

// ---------------- kernel 3: block-diag complex MLP, 32x32x16 MFMA ----------
// waves: wv = mh + 2*nh ; m-tile 32 per wave-half, n-half 96 per wave
// LDS: wr[96*104] | wi[96*104] | obuf[64*200]  (shorts) == 65,536 B
__global__ __launch_bounds__(256) void k_mlp(
    unsigned short* __restrict__ Sr, unsigned short* __restrict__ Si,
    const unsigned short* __restrict__ wbf,
    const float* __restrict__ b1, const float* __restrict__ b2) {
  __shared__ __align__(16) unsigned short smem[32768];
  unsigned short* wr   = smem;
  unsigned short* wi   = smem + 9984;
  unsigned short* obuf = smem + 19968;
  const int tid = threadIdx.x;
  const int kb  = blockIdx.x & 7;
  const int p0  = (blockIdx.x >> 3) * 64;
  const int wv  = tid >> 6, lane = tid & 63;
  const int mh = wv & 1, nh = wv >> 1;
  const int n32 = lane & 31, khalf = lane >> 5;

  // ---- stage layer-1 weights (two mats, 39,936 B contiguous) ----
  {
    const unsigned short* g = wbf + (size_t)kb * 19968;
    #pragma unroll
    for (int it = 0; it < 10; ++it) {
      int idx = tid + it * 256;
      if (idx < 2496) *(short8*)&smem[idx * 8] = *(const short8*)&g[idx * 8];
    }
  }
  __syncthreads();

  floatx16 acc[3];
  #pragma unroll
  for (int t = 0; t < 3; ++t)
    #pragma unroll
    for (int e = 0; e < 16; ++e) acc[t][e] = 0.0f;

  // ---- GEMM1: A = [Xr | Xi] (global bf16), B = Wc1 (LDS) ----
  const size_t arow = (size_t)(p0 + mh * 32 + n32) * C_ + kb * 96;
  #pragma unroll
  for (int kk = 0; kk < 12; ++kk) {
    const int kr = kk >= 6;
    const int kloc = (kk - kr * 6) * 16 + khalf * 8;   // k within 96-part
    const unsigned short* ap = (kr ? Si : Sr) + arow + kloc;
    short8 afr = *(const short8*)ap;
    const unsigned short* bb = (kr != nh) ? wi : wr;
    #pragma unroll
    for (int nt = 0; nt < 3; ++nt) {
      short8 bfr = *(const short8*)&bb[(nt * 32 + n32) * 104 + kloc];
      if (kr && !nh) {                                  // -Wi quadrant
        union { short8 s; int v[4]; } u; u.s = bfr;
        u.v[0] ^= 0x80008000; u.v[1] ^= 0x80008000;
        u.v[2] ^= 0x80008000; u.v[3] ^= 0x80008000;
        bfr = u.s;
      }
      acc[nt] = __builtin_amdgcn_mfma_f32_32x32x16_bf16(afr, bfr, acc[nt], 0, 0, 0);
    }
  }

  // ---- epilogue 1: bias + softshrink -> obuf (bf16, A-layout) ----
  #pragma unroll
  for (int nt = 0; nt < 3; ++nt) {
    const int o = nt * 32 + n32;
    const float bs = b1[(nh * 8 + kb) * 96 + o];
    const int n = nh * 96 + o;
    #pragma unroll
    for (int reg = 0; reg < 16; ++reg) {
      const int m = mh * 32 + (reg & 3) + 8 * (reg >> 2) + 4 * khalf;
      obuf[m * 200 + n] = f2bfu(softshrink(acc[nt][reg] + bs));
    }
  }
  __syncthreads();

  // ---- stage layer-2 weights over layer-1 ----
  {
    const unsigned short* g = wbf + (size_t)(8 + kb) * 19968;
    #pragma unroll
    for (int it = 0; it < 10; ++it) {
      int idx = tid + it * 256;
      if (idx < 2496) *(short8*)&smem[idx * 8] = *(const short8*)&g[idx * 8];
    }
  }
  __syncthreads();

  #pragma unroll
  for (int t = 0; t < 3; ++t)
    #pragma unroll
    for (int e = 0; e < 16; ++e) acc[t][e] = 0.0f;

  // ---- GEMM2: A from obuf (LDS), B = Wc2 (LDS) ----
  const int arow2 = (mh * 32 + n32) * 200;
  #pragma unroll
  for (int kk = 0; kk < 12; ++kk) {
    const int kr = kk >= 6;
    const int klocW = (kk - kr * 6) * 16 + khalf * 8;
    short8 afr = *(const short8*)&obuf[arow2 + kk * 16 + khalf * 8];
    const unsigned short* bb = (kr != nh) ? wi : wr;
    #pragma unroll
    for (int nt = 0; nt < 3; ++nt) {
      short8 bfr = *(const short8*)&bb[(nt * 32 + n32) * 104 + klocW];
      if (kr && !nh) {
        union { short8 s; int v[4]; } u; u.s = bfr;
        u.v[0] ^= 0x80008000; u.v[1] ^= 0x80008000;
        u.v[2] ^= 0x80008000; u.v[3] ^= 0x80008000;
        bfr = u.s;
      }
      acc[nt] = __builtin_amdgcn_mfma_f32_32x32x16_bf16(afr, bfr, acc[nt], 0, 0, 0);
    }
  }

  // ---- epilogue 2: bias + softshrink -> spectrum (bf16, in place) ----
  unsigned short* plane = nh ? Si : Sr;
  #pragma unroll
  for (int nt = 0; nt < 3; ++nt) {
    const int o = nt * 32 + n32;
    const float bs = b2[(nh * 8 + kb) * 96 + o];
    #pragma unroll
    for (int reg = 0; reg < 16; ++reg) {
      const int m = mh * 32 + (reg & 3) + 8 * (reg >> 2) + 4 * khalf;
      plane[(size_t)(p0 + m) * C_ + kb * 96 + o] = f2bfu(softshrink(acc[nt][reg] + bs));
    }
  }
}

// ---------------- kernel 5: irfft along W + residual -----------------------
__global__ __launch_bounds__(256) void k_irfft_w(
    const unsigned short* __restrict__ Sr, const unsigned short* __restrict__ Si,
    const float* __restrict__ xin, float* __restrict__ y,
    const float2* __restrict__ tw64g, const float2* __restrict__ tw128g) {
  __shared__ float2 stw64[32];
  __shared__ float2 stw128[65];
  const int tid = threadIdx.x;
  if (tid < 32) stw64[tid]  = tw64g[tid];
  if (tid < 65) stw128[tid] = tw128g[tid];
  __syncthreads();
  const int blk = blockIdx.x;
  const int cc = blk % 3, bh = blk / 3;
  const int c = cc * 256 + tid;
  const size_t ibase = (size_t)bh * (WF * C_) + c;
  float2 z[64];
  {
    float x0r  = bf2f(Sr[ibase]);
    float x64r = bf2f(Sr[ibase + (size_t)64 * C_]);
    z[0] = make_float2(0.5f * (x0r + x64r), 0.5f * (x0r - x64r));
  }
  #pragma unroll
  for (int k = 1; k <= 32; ++k) {
    float2 a, b;
    a.x = bf2f(Sr[ibase + (size_t)k * C_]);        a.y = bf2f(Si[ibase + (size_t)k * C_]);
    b.x = bf2f(Sr[ibase + (size_t)(64 - k) * C_]); b.y = bf2f(Si[ibase + (size_t)(64 - k) * C_]);
    float2 s = make_float2(0.5f * (a.x + b.x), 0.5f * (a.y - b.y));
    float2 d = make_float2(0.5f * (a.x - b.x), 0.5f * (a.y + b.y));
    float2 w = stw128[k]; w.y = -w.y;
    float2 zo = cmul(w, d);
    z[k] = make_float2(s.x - zo.y, s.y + zo.x);
    if (k < 32) z[64 - k] = make_float2(s.x + zo.y, zo.x - s.y);
  }
  fft64<1>(z, stw64);
  const float* xb = xin + (size_t)bh * (W_ * C_) + c;
  float*       yb = y   + (size_t)bh * (W_ * C_) + c;
  #pragma unroll
  for (int n = 0; n < 64; ++n) {
    yb[(size_t)(2 * n) * C_]     = z[n].x * (1.0f / 64.0f) + xb[(size_t)(2 * n) * C_];
    yb[(size_t)(2 * n + 1) * C_] = z[n].y * (1.0f / 64.0f) + xb[(size_t)(2 * n + 1) * C_];
  }
}

extern "C" void kernel_launch(void* const* d_in, const int* in_sizes, int n_in,
                              void* d_out, int out_size, void* d_ws, size_t ws_size,
                              hipStream_t stream) {
  const float* x  = (const float*)d_in[0];
  const float* w1 = (const float*)d_in[1];
  const float* w2 = (const float*)d_in[2];
  const float* b1 = (const float*)d_in[3];
  const float* b2 = (const float*)d_in[4];
  float* y = (float*)d_out;

  float2* tw64  = (float2*)d_ws;
  float2* tw128 = tw64 + 32;
  unsigned short* wbf = (unsigned short*)((char*)d_ws + 1024);      // 319,488 shorts
  unsigned short* Sr  = (unsigned short*)((char*)d_ws + (1 << 20));
  unsigned short* Si  = Sr + PLANE;

  k_init_tw<<<1, 128, 0, stream>>>(tw64, tw128);
  k_wconv<<<dim3(1248), dim3(256), 0, stream>>>(w1, w2, wbf);
  k_rfft_w<<<dim3(B_ * H_ * 3), dim3(256), 0, stream>>>(x, Sr, Si, tw64, tw128);
  k_fft_h<-1><<<dim3(B_ * WF * 12), dim3(128), 0, stream>>>(Sr, Si, tw64, tw128);
  k_mlp<<<dim3(520 * 8), dim3(256), 0, stream>>>(Sr, Si, wbf, b1, b2);
  k_fft_h<1><<<dim3(B_ * WF * 12), dim3(128), 0, stream>>>(Sr, Si, tw64, tw128);
  k_irfft_w<<<dim3(B_ * H_ * 3), dim3(256), 0, stream>>>(Sr, Si, x, y, tw64, tw128);
}